// Round 9
// baseline (138.132 us; speedup 1.0000x reference)
//
#include <hip/hip_runtime.h>

#define N_NODES 10000
#define N_EDGES 640000
#define D 128
#define CAP 128          // per-bin csr capacity; max in-degree ~101 (verified prior session)

typedef unsigned long long ull;
typedef unsigned short u16;
typedef unsigned int u32;

#define CHUNKS 128
#define EPC 5000                             // 128 * 5000 = 640000 exactly
#define NR 500                               // dst ranges
#define RW 20                                // bins per range; 500*20 = 10000 exact
#define CELLCAP 40                           // lambda=10 per cell; P(any overflow)~4e-8, clamped
#define RECS 10                              // CHUNKS*CELLCAP/512 staged records per thread
#define GEMM_NPB 32
#define GEMM_BLOCKS ((N_NODES + GEMM_NPB - 1) / GEMM_NPB)   // 313
#define SMEM_K1 16384                        // gemm tile; edge blocks use 2KB for rcnt
// packed u32 (gpacked): count in bits 25..31 (max deg 101 < 128),
// ew-sum in bits 0..24 as 7.18 fixed point (sum <= 102 -> 26.7M < 2^25)
#define EWFX 262144.0f                       // 2^18
#define EWM  0x1ffffffu                      // low 25 bits

__device__ __forceinline__ u16 f2bf(float f) {
    unsigned u = __float_as_uint(f);
    unsigned r = (u + 0x7fffu + ((u >> 16) & 1u)) >> 16;   // round-to-nearest-even
    return (u16)r;
}

// ---- K1 (k_bucket): bucket edges by range + NON-RETURN global deg atomics + gemm ----
// R8 post-mortem: no single hot kernel left; remaining cost is dispatch count +
// csr round-trip + agg setup. The 12 G/s atomic wall (R0-R3) was for RETURN
// atomics; fire-and-forget atomicAdd has no dependent use and pipelines behind
// the scatter stores. gpacked (deg|ewsum) complete at K1 end -> K2 can fuse
// rank+aggregate per range with csr living entirely in LDS.

__global__ void __launch_bounds__(256) k_bucket(
    const int* __restrict__ src, const int* __restrict__ dst,
    const float* __restrict__ ew, const float* __restrict__ x,
    const float* __restrict__ W, u16* __restrict__ h_bf,
    u32* __restrict__ counts, ull* __restrict__ ebuf, u32* __restrict__ gpacked)
{
    extern __shared__ char smem[];
    const int t = threadIdx.x;

    if (blockIdx.x < CHUNKS) {
        // ---- edge path: count + scatter 8B records into (range, chunk) cells ----
        u32* rcnt = (u32*)smem;                       // 500 counters
        for (int i = t; i < NR; i += 256) rcnt[i] = 0;
        __syncthreads();

        const int e0 = blockIdx.x * EPC;
        #pragma unroll
        for (int i = 0; i < 20; ++i) {                // 20*256 = 5120 >= 5000
            int idx = i * 256 + t;
            if (idx < EPC) {
                int e = e0 + idx;
                int d = dst[e];
                int s = src[e];
                float w = ew[e];
                u32 add = (1u << 25) | (u32)(w * EWFX);
                atomicAdd(&gpacked[d], add);          // non-return: fire-and-forget
                int r = d / RW;                       // magic-mul
                int bin = d - r * RW;                 // 0..19 (5 bits)
                u32 slot = atomicAdd(&rcnt[r], 1u);   // LDS return-atomic
                if (slot < CELLCAP) {
                    ebuf[((size_t)r * CHUNKS + blockIdx.x) * CELLCAP + slot] =
                        ((ull)__float_as_uint(w) << 32) | ((u32)s << 5) | (u32)bin;
                }
            }
        }
        __syncthreads();

        for (int i = t; i < NR; i += 256) counts[blockIdx.x * NR + i] = rcnt[i];
    } else {
        // ---- gemm path (overlaps): h = x @ W^T -> bf16, 32 nodes/block ----
        float* xs = (float*)smem;                     // [32][128] = 16 KB
        const int node0 = (blockIdx.x - CHUNKS) * GEMM_NPB;
        const int col = t & 127;
        const int half = t >> 7;

        #pragma unroll
        for (int r = 0; r < 16; ++r) {
            int row = half * 16 + r;
            int n = node0 + row;
            xs[row * D + col] = (n < N_NODES) ? x[n * D + col] : 0.0f;
        }
        __syncthreads();

        float acc[16];
        #pragma unroll
        for (int r = 0; r < 16; ++r) acc[r] = 0.0f;

        const float4* Wrow = (const float4*)&W[col * D];
        const float* xbase = &xs[half * 16 * D];
        for (int k4 = 0; k4 < D / 4; ++k4) {
            float4 w = Wrow[k4];
            int k = k4 * 4;
            #pragma unroll
            for (int r = 0; r < 16; ++r) {
                acc[r] += xbase[r * D + k + 0] * w.x;
                acc[r] += xbase[r * D + k + 1] * w.y;
                acc[r] += xbase[r * D + k + 2] * w.z;
                acc[r] += xbase[r * D + k + 3] * w.w;
            }
        }
        #pragma unroll
        for (int r = 0; r < 16; ++r) {
            int n = node0 + half * 16 + r;
            if (n < N_NODES) h_bf[n * D + col] = f2bf(acc[r]);
        }
    }
}

// ---- K2 (k_range): rank + aggregate fused; csr lives in LDS only ----
// Stage column to REGISTERS (10 coalesced 8B loads/thread), rank into a 20KB
// LDS csr computing norms from L2-hot gpacked, then each wave aggregates its
// bins with the k_agg inner loop. Deletes: csr global round-trip (10MB),
// k_agg's setup phase, one launch+gap.

__global__ void __launch_bounds__(512) k_range(
    const u32* __restrict__ counts, const ull* __restrict__ ebuf,
    const u32* __restrict__ gpacked, const u16* __restrict__ h_bf,
    const float* __restrict__ b, float* __restrict__ out)
{
    __shared__ ull csr_s[RW * CAP];                   // 20 KB: (norm_f32<<32)|src
    __shared__ u32 bcnt[RW];
    __shared__ u32 ccnt[CHUNKS];
    const int t = threadIdx.x;
    const int r = blockIdx.x;

    // stage whole column into registers (coalesced, independent)
    ull rec[RECS];
    const ull* colg = ebuf + (size_t)r * CHUNKS * CELLCAP;
    #pragma unroll
    for (int i = 0; i < RECS; ++i) rec[i] = colg[i * 512 + t];

    if (t < RW) bcnt[t] = 0;
    if (t < CHUNKS) {
        u32 c = counts[t * NR + r];
        ccnt[t] = (c > CELLCAP) ? (u32)CELLCAP : c;   // hardening
    }
    __syncthreads();

    // rank + norm: idx -> (chunk, slot); valid if slot < ccnt[chunk]
    #pragma unroll
    for (int i = 0; i < RECS; ++i) {
        int idx = i * 512 + t;
        int c = idx / CELLCAP;                        // magic-mul (const 40)
        int slot = idx - c * CELLCAP;
        if (slot < (int)ccnt[c]) {
            ull rv = rec[i];
            u32 lo = (u32)rv;
            int bin = (int)(lo & 31u);
            int s = (int)(lo >> 5);
            float w = __uint_as_float((u32)(rv >> 32));
            u32 gps = gpacked[s];                     // 40KB table, L2-hot
            u32 gpn = gpacked[r * RW + bin];
            float ds_ = rsqrtf(1.0f + (float)(gps & EWM) * 0x1p-18f);
            float dn  = rsqrtf(1.0f + (float)(gpn & EWM) * 0x1p-18f);
            float nm = ds_ * w * dn;
            u32 pos = atomicAdd(&bcnt[bin], 1u);      // LDS return-atomic
            if (pos < CAP)
                csr_s[bin * CAP + pos] = ((ull)__float_as_uint(nm) << 32) | (u32)s;
        }
    }
    __syncthreads();

    // aggregate: wave w handles bins w, w+8, w+16; 64 lanes x 2 cols
    const int wid  = t >> 6;
    const int lane = t & 63;
    float2 bb = *(const float2*)(b + lane * 2);
    for (int bin = wid; bin < RW; bin += 8) {
        const int n = r * RW + bin;
        const int cnt = (int)bcnt[bin];
        float acc0 = 0.0f, acc1 = 0.0f;
        const ull* cl = csr_s + bin * CAP;
        #pragma unroll 4
        for (int j = 0; j < cnt; ++j) {
            ull v = cl[j];                            // uniform addr -> LDS broadcast
            int s = (int)(u32)v;
            float nm = __uint_as_float((u32)(v >> 32));
            u32 hc = *(const u32*)(h_bf + (size_t)s * D + lane * 2);
            acc0 += __uint_as_float(hc << 16) * nm;
            acc1 += __uint_as_float(hc & 0xffff0000u) * nm;
        }
        u32 gpn = gpacked[n];
        float dn = rsqrtf(1.0f + (float)(gpn & EWM) * 0x1p-18f);
        float s2 = dn * dn;
        u32 hs = *(const u32*)(h_bf + (size_t)n * D + lane * 2);
        acc0 += __uint_as_float(hs << 16) * s2;
        acc1 += __uint_as_float(hs & 0xffff0000u) * s2;
        float2 o;
        o.x = acc0 + bb.x;
        o.y = acc1 + bb.y;
        *(float2*)(out + (size_t)n * D + lane * 2) = o;
    }
}

// ---------------- launch ----------------

extern "C" void kernel_launch(void* const* d_in, const int* in_sizes, int n_in,
                              void* d_out, int out_size, void* d_ws, size_t ws_size,
                              hipStream_t stream) {
    const float* x  = (const float*)d_in[0];
    const float* W  = (const float*)d_in[1];
    const float* b  = (const float*)d_in[2];
    const float* ew = (const float*)d_in[3];
    const int* ei   = (const int*)d_in[4];
    const int* src = ei;
    const int* dst = ei + N_EDGES;
    float* out = (float*)d_out;

    // workspace layout (bytes), ws >= 268 MB per fillBuffer evidence:
    // gpacked u32[10000]            [0,        40000)     (memset to 0)
    // h_bf    u16[10000*128]        [40000,    2600000)
    // counts  u32[128*500]          [2600000,  2856000)
    // ebuf    u64[500*128*40]       [2856000,  23336000)  (8B aligned)
    char* ws = (char*)d_ws;
    u32*   gpacked = (u32*)(ws);
    u16*   h_bf    = (u16*)(ws + 40000);
    u32*   counts  = (u32*)(ws + 2600000);
    ull*   ebuf    = (ull*)(ws + 2856000);

    hipMemsetAsync(gpacked, 0, 40000, stream);
    k_bucket<<<CHUNKS + GEMM_BLOCKS, 256, SMEM_K1, stream>>>(
        src, dst, ew, x, W, h_bf, counts, ebuf, gpacked);
    k_range<<<NR, 512, 0, stream>>>(counts, ebuf, gpacked, h_bf, b, out);
}

// Round 10
// 123.391 us; speedup vs baseline: 1.1195x; 1.1195x over previous
//
#include <hip/hip_runtime.h>

#define N_NODES 10000
#define N_EDGES 640000
#define D 128
#define CAP 128          // per-bin csr capacity; max in-degree ~101 (verified prior session)

typedef unsigned long long ull;
typedef unsigned short u16;
typedef unsigned int u32;

#define CHUNKS 128
#define EPC 5000                             // 128 * 5000 = 640000 exactly
#define NR 500                               // dst ranges
#define RW 20                                // bins per range; 500*20 = 10000 exact
#define CELLCAP 40                           // lambda=10 per cell; P(any overflow)~4e-8; config verified R9
#define RECS 10                              // CHUNKS*CELLCAP/512 staged records per thread (k_range)
#define GEMM_NPB 32
#define GEMM_BLOCKS ((N_NODES + GEMM_NPB - 1) / GEMM_NPB)   // 313
#define SMEM_K1 16384                        // gemm tile; edge blocks use 2KB for rcnt
#define EWFX 262144.0f                       // 2^18 fixed-point scale for ew sums
// R9 post-mortem: 640k NON-return global atomics cost ~35us (18 G/s) -- the
// atomic wall is coherence-point update throughput, not return dependence.
// Zero global atomics anywhere in this version.

__device__ __forceinline__ u16 f2bf(float f) {
    unsigned u = __float_as_uint(f);
    unsigned r = (u + 0x7fffu + ((u >> 16) & 1u)) >> 16;   // round-to-nearest-even
    return (u16)r;
}

// ---- K1 (k_bucket): bucket edges by dst-range + fused gemm; NO global atomics ----

__global__ void __launch_bounds__(256) k_bucket(
    const int* __restrict__ src, const int* __restrict__ dst,
    const float* __restrict__ ew, const float* __restrict__ x,
    const float* __restrict__ W, u16* __restrict__ h_bf,
    u32* __restrict__ counts, ull* __restrict__ ebuf)
{
    extern __shared__ char smem[];
    const int t = threadIdx.x;

    if (blockIdx.x < CHUNKS) {
        // ---- edge path: count + scatter 8B records into (range, chunk) cells ----
        u32* rcnt = (u32*)smem;                       // 500 counters
        for (int i = t; i < NR; i += 256) rcnt[i] = 0;
        __syncthreads();

        const int e0 = blockIdx.x * EPC;
        #pragma unroll
        for (int i = 0; i < 20; ++i) {                // 20*256 = 5120 >= 5000
            int idx = i * 256 + t;
            if (idx < EPC) {
                int e = e0 + idx;
                int d = dst[e];
                int s = src[e];
                float w = ew[e];
                int r = d / RW;                       // magic-mul
                int bin = d - r * RW;                 // 0..19 (5 bits)
                u32 slot = atomicAdd(&rcnt[r], 1u);   // LDS return-atomic (CU-local)
                if (slot < CELLCAP) {
                    ebuf[((size_t)r * CHUNKS + blockIdx.x) * CELLCAP + slot] =
                        ((ull)__float_as_uint(w) << 32) | ((u32)s << 5) | (u32)bin;
                }
            }
        }
        __syncthreads();

        for (int i = t; i < NR; i += 256) counts[blockIdx.x * NR + i] = rcnt[i];
    } else {
        // ---- gemm path (overlaps): h = x @ W^T -> bf16, 32 nodes/block ----
        float* xs = (float*)smem;                     // [32][128] = 16 KB
        const int node0 = (blockIdx.x - CHUNKS) * GEMM_NPB;
        const int col = t & 127;
        const int half = t >> 7;

        #pragma unroll
        for (int r = 0; r < 16; ++r) {
            int row = half * 16 + r;
            int n = node0 + row;
            xs[row * D + col] = (n < N_NODES) ? x[n * D + col] : 0.0f;
        }
        __syncthreads();

        float acc[16];
        #pragma unroll
        for (int r = 0; r < 16; ++r) acc[r] = 0.0f;

        const float4* Wrow = (const float4*)&W[col * D];
        const float* xbase = &xs[half * 16 * D];
        for (int k4 = 0; k4 < D / 4; ++k4) {
            float4 w = Wrow[k4];
            int k = k4 * 4;
            #pragma unroll
            for (int r = 0; r < 16; ++r) {
                acc[r] += xbase[r * D + k + 0] * w.x;
                acc[r] += xbase[r * D + k + 1] * w.y;
                acc[r] += xbase[r * D + k + 2] * w.z;
                acc[r] += xbase[r * D + k + 3] * w.w;
            }
        }
        #pragma unroll
        for (int r = 0; r < 16; ++r) {
            int n = node0 + half * 16 + r;
            if (n < N_NODES) h_bf[n * D + col] = f2bf(acc[r]);
        }
    }
}

// ---- K2 (k_dinv): feather-weight dinv publisher ----
// Per range: stream its 40KB column (coalesced, independent), sum ewsum/bin
// via LDS non-return atomics (fixed-point -> deterministic), write dinv[20].
// Exists solely to cross the grid-wide dinv dependency at dispatch-gap cost.

__global__ void __launch_bounds__(256) k_dinv(
    const u32* __restrict__ counts, const ull* __restrict__ ebuf,
    float* __restrict__ dinv)
{
    __shared__ u32 bsum[RW];                          // ewsum 7.18 fixed (max 26.7M < 2^32)
    __shared__ u32 ccnt[CHUNKS];
    const int t = threadIdx.x;
    const int r = blockIdx.x;

    if (t < RW) bsum[t] = 0;
    if (t < CHUNKS) {
        u32 c = counts[t * NR + r];
        ccnt[t] = (c > CELLCAP) ? (u32)CELLCAP : c;   // hardening
    }
    __syncthreads();

    const ull* colg = ebuf + (size_t)r * CHUNKS * CELLCAP;
    #pragma unroll
    for (int i = 0; i < 20; ++i) {                    // 5120 records / 256 threads
        int idx = i * 256 + t;
        int c = idx / CELLCAP;                        // magic-mul (const 40)
        int slot = idx - c * CELLCAP;
        if (slot < (int)ccnt[c]) {
            ull rv = colg[idx];
            int bin = (int)((u32)rv & 31u);
            float w = __uint_as_float((u32)(rv >> 32));
            atomicAdd(&bsum[bin], (u32)(w * EWFX));   // LDS non-return atomic
        }
    }
    __syncthreads();

    if (t < RW)
        dinv[r * RW + t] = rsqrtf(1.0f + (float)bsum[t] * 0x1p-18f);
}

// ---- K3 (k_range): rank + aggregate fused; csr lives in LDS only ----
// Stage column to registers (10 coalesced 8B loads/thread), rank into a 20KB
// LDS csr with norm = dinv[s] * w * dinv[d] (one L2-hot gather + one LDS read),
// then each wave aggregates its bins. No csr global round-trip, no agg setup.

__global__ void __launch_bounds__(512) k_range(
    const u32* __restrict__ counts, const ull* __restrict__ ebuf,
    const float* __restrict__ dinv, const u16* __restrict__ h_bf,
    const float* __restrict__ b, float* __restrict__ out)
{
    __shared__ ull csr_s[RW * CAP];                   // 20 KB: (norm_f32<<32)|src
    __shared__ u32 bcnt[RW];
    __shared__ u32 ccnt[CHUNKS];
    __shared__ float ldin[RW];
    const int t = threadIdx.x;
    const int r = blockIdx.x;

    // stage whole column into registers (coalesced, independent)
    ull rec[RECS];
    const ull* colg = ebuf + (size_t)r * CHUNKS * CELLCAP;
    #pragma unroll
    for (int i = 0; i < RECS; ++i) rec[i] = colg[i * 512 + t];

    if (t < RW) {
        bcnt[t] = 0;
        ldin[t] = dinv[r * RW + t];
    }
    if (t < CHUNKS) {
        u32 c = counts[t * NR + r];
        ccnt[t] = (c > CELLCAP) ? (u32)CELLCAP : c;   // hardening
    }
    __syncthreads();

    // rank + norm: idx -> (chunk, slot); valid if slot < ccnt[chunk]
    #pragma unroll
    for (int i = 0; i < RECS; ++i) {
        int idx = i * 512 + t;
        int c = idx / CELLCAP;                        // magic-mul (const 40)
        int slot = idx - c * CELLCAP;
        if (slot < (int)ccnt[c]) {
            ull rv = rec[i];
            u32 lo = (u32)rv;
            int bin = (int)(lo & 31u);
            int s = (int)(lo >> 5);
            float w = __uint_as_float((u32)(rv >> 32));
            float nm = dinv[s] * w * ldin[bin];       // 40KB table, L2-hot
            u32 pos = atomicAdd(&bcnt[bin], 1u);      // LDS return-atomic
            if (pos < CAP)
                csr_s[bin * CAP + pos] = ((ull)__float_as_uint(nm) << 32) | (u32)s;
        }
    }
    __syncthreads();

    // aggregate: wave w handles bins w, w+8, w+16; 64 lanes x 2 cols
    const int wid  = t >> 6;
    const int lane = t & 63;
    float2 bb = *(const float2*)(b + lane * 2);
    for (int bin = wid; bin < RW; bin += 8) {
        const int n = r * RW + bin;
        const int cnt = (int)bcnt[bin];
        float acc0 = 0.0f, acc1 = 0.0f;
        const ull* cl = csr_s + bin * CAP;
        #pragma unroll 4
        for (int j = 0; j < cnt; ++j) {
            ull v = cl[j];                            // uniform addr -> LDS broadcast
            int s = (int)(u32)v;
            float nm = __uint_as_float((u32)(v >> 32));
            u32 hc = *(const u32*)(h_bf + (size_t)s * D + lane * 2);
            acc0 += __uint_as_float(hc << 16) * nm;
            acc1 += __uint_as_float(hc & 0xffff0000u) * nm;
        }
        float dn = ldin[bin];
        float s2 = dn * dn;
        u32 hs = *(const u32*)(h_bf + (size_t)n * D + lane * 2);
        acc0 += __uint_as_float(hs << 16) * s2;
        acc1 += __uint_as_float(hs & 0xffff0000u) * s2;
        float2 o;
        o.x = acc0 + bb.x;
        o.y = acc1 + bb.y;
        *(float2*)(out + (size_t)n * D + lane * 2) = o;
    }
}

// ---------------- launch ----------------

extern "C" void kernel_launch(void* const* d_in, const int* in_sizes, int n_in,
                              void* d_out, int out_size, void* d_ws, size_t ws_size,
                              hipStream_t stream) {
    const float* x  = (const float*)d_in[0];
    const float* W  = (const float*)d_in[1];
    const float* b  = (const float*)d_in[2];
    const float* ew = (const float*)d_in[3];
    const int* ei   = (const int*)d_in[4];
    const int* src = ei;
    const int* dst = ei + N_EDGES;
    float* out = (float*)d_out;

    // workspace layout (bytes), ws >= 268 MB per fillBuffer evidence:
    // dinv    f32[10000]            [0,        40000)
    // h_bf    u16[10000*128]        [40000,    2600000)
    // counts  u32[128*500]          [2600000,  2856000)
    // ebuf    u64[500*128*40]       [2856000,  23336000)  (8B aligned)
    char* ws = (char*)d_ws;
    float* dinv    = (float*)(ws);
    u16*   h_bf    = (u16*)(ws + 40000);
    u32*   counts  = (u32*)(ws + 2600000);
    ull*   ebuf    = (ull*)(ws + 2856000);

    k_bucket<<<CHUNKS + GEMM_BLOCKS, 256, SMEM_K1, stream>>>(
        src, dst, ew, x, W, h_bf, counts, ebuf);
    k_dinv<<<NR, 256, 0, stream>>>(counts, ebuf, dinv);
    k_range<<<NR, 512, 0, stream>>>(counts, ebuf, dinv, h_bf, b, out);
}

// Round 11
// 121.850 us; speedup vs baseline: 1.1336x; 1.0127x over previous
//
#include <hip/hip_runtime.h>

#define N_NODES 10000
#define N_EDGES 640000
#define D 128
#define CAP 128          // per-bin csr capacity; max in-degree ~101 (verified prior session)

typedef unsigned long long ull;
typedef unsigned short u16;
typedef unsigned int u32;

#define CHUNKS 512                           // R10 post-mortem: 128 chunks = 1.7 blocks/CU, Occ 11%
#define EPC 1250                             // 512 * 1250 = 640000 exactly
#define NR 500                               // dst ranges
#define RW 20                                // bins per range; 500*20 = 10000 exact
#define CELLCAP 20                           // lambda=2.5/cell; P(any cell >20) ~1e-7, clamped
#define GEMM_NPB 32
#define GEMM_BLOCKS ((N_NODES + GEMM_NPB - 1) / GEMM_NPB)   // 313
#define SMEM_K1 16384                        // gemm tile; edge blocks use 2KB for rcnt
#define EWFX 262144.0f                       // 2^18 fixed-point scale for ew sums
#define EWM  0x1ffffffu                      // low 25 bits of packed gpacked
// Session laws: return-atomics ~12 G/s, non-return ~43 G/s (both too slow for
// 640k on the critical path); grid.sync ~40us; LDS atomics cheap (CU-local).
// Budget anchors: fill=44 (harness, fixed), R8 best=115.1 with k_bucket~35.

__device__ __forceinline__ u16 f2bf(float f) {
    unsigned u = __float_as_uint(f);
    unsigned r = (u + 0x7fffu + ((u >> 16) & 1u)) >> 16;   // round-to-nearest-even
    return (u16)r;
}

// ---- K1 (k_bucket): bucket edges by dst-range + fused gemm; NO global atomics ----
// 512 chunk blocks + 313 gemm blocks = 825 (~3.2/CU). Each edge: LDS
// return-atomic slot in rcnt[range], 8B record store into the (range,chunk)
// cell. Cell end marked by an in-band terminator (bin-field=31) -> no counts[].

__global__ void __launch_bounds__(256) k_bucket(
    const int* __restrict__ src, const int* __restrict__ dst,
    const float* __restrict__ ew, const float* __restrict__ x,
    const float* __restrict__ W, u16* __restrict__ h_bf,
    ull* __restrict__ ebuf)
{
    extern __shared__ char smem[];
    const int t = threadIdx.x;

    if (blockIdx.x < CHUNKS) {
        // ---- edge path ----
        u32* rcnt = (u32*)smem;                       // 500 counters
        for (int i = t; i < NR; i += 256) rcnt[i] = 0;
        __syncthreads();

        const int e0 = blockIdx.x * EPC;
        #pragma unroll
        for (int i = 0; i < 5; ++i) {                 // 5*256 = 1280 >= 1250
            int idx = i * 256 + t;
            if (idx < EPC) {
                int e = e0 + idx;
                int d = dst[e];
                int s = src[e];
                float w = ew[e];
                int r = d / RW;                       // magic-mul
                int bin = d - r * RW;                 // 0..19 (5 bits; 31 = terminator)
                u32 slot = atomicAdd(&rcnt[r], 1u);   // LDS return-atomic (CU-local)
                if (slot < CELLCAP) {
                    ebuf[((size_t)r * CHUNKS + blockIdx.x) * CELLCAP + slot] =
                        ((ull)__float_as_uint(w) << 32) | ((u32)s << 5) | (u32)bin;
                }
            }
        }
        __syncthreads();

        // in-band terminators (cell full -> none needed; k_csr clamps to CELLCAP)
        for (int i = t; i < NR; i += 256) {
            u32 slot = rcnt[i];
            if (slot < CELLCAP)
                ebuf[((size_t)i * CHUNKS + blockIdx.x) * CELLCAP + slot] = 31ull;
        }
    } else {
        // ---- gemm path (overlaps): h = x @ W^T -> bf16, 32 nodes/block ----
        float* xs = (float*)smem;                     // [32][128] = 16 KB
        const int node0 = (blockIdx.x - CHUNKS) * GEMM_NPB;
        const int col = t & 127;
        const int half = t >> 7;

        #pragma unroll
        for (int r = 0; r < 16; ++r) {
            int row = half * 16 + r;
            int n = node0 + row;
            xs[row * D + col] = (n < N_NODES) ? x[n * D + col] : 0.0f;
        }
        __syncthreads();

        float acc[16];
        #pragma unroll
        for (int r = 0; r < 16; ++r) acc[r] = 0.0f;

        const float4* Wrow = (const float4*)&W[col * D];
        const float* xbase = &xs[half * 16 * D];
        for (int k4 = 0; k4 < D / 4; ++k4) {
            float4 w = Wrow[k4];
            int k = k4 * 4;
            #pragma unroll
            for (int r = 0; r < 16; ++r) {
                acc[r] += xbase[r * D + k + 0] * w.x;
                acc[r] += xbase[r * D + k + 1] * w.y;
                acc[r] += xbase[r * D + k + 2] * w.z;
                acc[r] += xbase[r * D + k + 3] * w.w;
            }
        }
        #pragma unroll
        for (int r = 0; r < 16; ++r) {
            int n = node0 + half * 16 + r;
            if (n < N_NODES) h_bf[n * D + col] = f2bf(acc[r]);
        }
    }
}

// ---- K2 (k_csr): one THREAD per (range,chunk) cell; register-staged rank ----
// 500 blocks x 512 threads (1 thread = 1 chunk's cell, CHUNKS == blockDim).
// Prefetch own 160B cell into registers (compile-time-const indexing only),
// find terminator, rank via packed LDS return-atomics, store 8B csr records.
// No LDS stage, no counts traffic. Writes gpacked (deg|ewsum) + dinv.

#define REC(s) (((s) & 1) ? (((ull)rr[(s) >> 1].w << 32) | (ull)rr[(s) >> 1].z) \
                          : (((ull)rr[(s) >> 1].y << 32) | (ull)rr[(s) >> 1].x))

__global__ void __launch_bounds__(512) k_csr(
    const ull* __restrict__ ebuf, u32* __restrict__ gpacked,
    float* __restrict__ dinv, ull* __restrict__ csr)
{
    __shared__ u32 bcnt[RW];                          // packed count<<25 | ewsum_7.18
    const int t = threadIdx.x;
    const int r = blockIdx.x;

    if (t < RW) bcnt[t] = 0;

    // prefetch own cell (10 x uint4, coalesced-via-L1 within the 80KB column)
    uint4 rr[CELLCAP / 2];
    const uint4* pb = (const uint4*)(ebuf + ((size_t)r * CHUNKS + t) * CELLCAP);
    #pragma unroll
    for (int i = 0; i < CELLCAP / 2; ++i) rr[i] = pb[i];
    __syncthreads();                                  // bcnt init visible

    // count = index of first terminator (bin-field == 31); no terminator -> full
    int cnt = CELLCAP;
    #pragma unroll
    for (int s = CELLCAP - 1; s >= 0; --s)
        if (((u32)REC(s) & 31u) == 31u) cnt = s;

    #pragma unroll
    for (int s = 0; s < CELLCAP; ++s) {
        if (s < cnt) {
            ull v = REC(s);
            u32 lo = (u32)v;
            int bin = (int)(lo & 31u);
            u32 srcn = lo >> 5;
            u32 wb = (u32)(v >> 32);
            float w = __uint_as_float(wb);
            u32 add = (1u << 25) | (u32)(w * EWFX);
            u32 old = atomicAdd(&bcnt[bin], add);     // LDS return-atomic
            int pos = (int)(old >> 25);
            if (pos < CAP) {
                int dstg = r * RW + bin;
                csr[(size_t)dstg * CAP + pos] = ((ull)wb << 32) | srcn;
            }
        }
    }
    __syncthreads();

    if (t < RW) {
        int n = r * RW + t;
        u32 v = bcnt[t];
        gpacked[n] = v;
        dinv[n] = rsqrtf(1.0f + (float)(v & EWM) * 0x1p-18f);
    }
}

// ---- K3 (k_agg): one WAVE per node (byte-identical to R8's best) ----

#define AGG_NPB 4                         // nodes (waves) per 256-thread block

__global__ void __launch_bounds__(256) k_agg(
    const u32* __restrict__ gpacked, const float* __restrict__ dinv,
    const ull* __restrict__ csr, const u16* __restrict__ h_bf,
    const float* __restrict__ b, float* __restrict__ out)
{
    const int wid  = threadIdx.x >> 6;
    const int lane = threadIdx.x & 63;
    const int n = blockIdx.x * AGG_NPB + wid;   // 2500*4 = 10000 exact

    __shared__ ull sm[AGG_NPB][CAP];            // packed (norm_f32 << 32) | src

    const int deg = (int)(gpacked[n] >> 25);
    const float dn = dinv[n];
    const ull* bucket = csr + (size_t)n * CAP;

    #pragma unroll
    for (int r = 0; r < 2; ++r) {
        int j = r * 64 + lane;
        if (j < deg) {
            ull v = bucket[j];
            int s = (int)(u32)(v & 0xffffffffu);
            float w = __uint_as_float((u32)(v >> 32));
            float nm = dinv[s] * w * dn;        // table gather, 40KB L2-hot
            sm[wid][j] = ((ull)__float_as_uint(nm) << 32) | (u32)s;
        }
    }
    __syncthreads();                            // setup->mainloop; waves independent after

    float acc0 = 0.0f, acc1 = 0.0f;
    const ull* smw = sm[wid];
    #pragma unroll 4
    for (int j = 0; j < deg; ++j) {
        ull v = smw[j];                         // same addr across wave -> LDS broadcast
        int s = (int)(u32)v;
        float nm = __uint_as_float((u32)(v >> 32));
        u32 hc = *(const u32*)(h_bf + (size_t)s * D + lane * 2);  // 2 bf16 cols
        acc0 += __uint_as_float(hc << 16) * nm;
        acc1 += __uint_as_float(hc & 0xffff0000u) * nm;
    }

    // self loop + bias, write 8B/lane (512B/wave contiguous)
    float s2 = dn * dn;
    u32 hs = *(const u32*)(h_bf + (size_t)n * D + lane * 2);
    acc0 += __uint_as_float(hs << 16) * s2;
    acc1 += __uint_as_float(hs & 0xffff0000u) * s2;
    float2 bb = *(const float2*)(b + lane * 2);
    float2 o;
    o.x = acc0 + bb.x;
    o.y = acc1 + bb.y;
    *(float2*)(out + (size_t)n * D + lane * 2) = o;
}

// ---------------- launch ----------------

extern "C" void kernel_launch(void* const* d_in, const int* in_sizes, int n_in,
                              void* d_out, int out_size, void* d_ws, size_t ws_size,
                              hipStream_t stream) {
    const float* x  = (const float*)d_in[0];
    const float* W  = (const float*)d_in[1];
    const float* b  = (const float*)d_in[2];
    const float* ew = (const float*)d_in[3];
    const int* ei   = (const int*)d_in[4];
    const int* src = ei;
    const int* dst = ei + N_EDGES;
    float* out = (float*)d_out;

    // workspace layout (bytes), ws >= 268 MB per fillBuffer evidence:
    // gpacked u32[10000]            [0,        40000)
    // dinv    f32[10000]            [40000,    80000)
    // h_bf    u16[10000*128]        [80000,    2640000)
    // csr     u64[10000*128]        [2640000,  12880000)
    // ebuf    u64[500*512*20]       [12880000, 53840000)  (16B aligned)
    char* ws = (char*)d_ws;
    u32*   gpacked = (u32*)(ws);
    float* dinv    = (float*)(ws + 40000);
    u16*   h_bf    = (u16*)(ws + 80000);
    ull*   csr     = (ull*)(ws + 2640000);
    ull*   ebuf    = (ull*)(ws + 12880000);

    k_bucket<<<CHUNKS + GEMM_BLOCKS, 256, SMEM_K1, stream>>>(
        src, dst, ew, x, W, h_bf, ebuf);
    k_csr<<<NR, 512, 0, stream>>>(ebuf, gpacked, dinv, csr);
    k_agg<<<N_NODES / AGG_NPB, 256, 0, stream>>>(gpacked, dinv, csr, h_bf, b, out);
}

// Round 12
// 116.932 us; speedup vs baseline: 1.1813x; 1.0421x over previous
//
#include <hip/hip_runtime.h>

#define N_NODES 10000
#define N_EDGES 640000
#define D 128
#define CAP 128          // per-bin csr capacity; max in-degree ~101 (verified prior session)

typedef unsigned long long ull;
typedef unsigned short u16;
typedef unsigned int u32;

#define CHUNKS 512                           // == k_csr blockDim (1 thread : 1 chunk)
#define EPC 1250                             // 512 * 1250 = 640000 exactly
#define NR 500                               // dst ranges
#define RW 20                                // bins per range; 500*20 = 10000 exact
#define GEMM_NPB 32
#define GEMM_BLOCKS ((N_NODES + GEMM_NPB - 1) / GEMM_NPB)   // 313
#define SMEM_K1 16384                        // edge: rcnt2K+ping2K+pong2K+sorted10K; gemm: 16K tile
#define EWFX 262144.0f                       // 2^18 fixed-point scale for ew sums
#define EWM  0x1ffffffu                      // low 25 bits of packed gpacked
// Session laws: global atomics 640k ~35-50us (return or not) -> banned on hot
// path. grid.sync ~40us -> banned. Scattered 8B stores: cheap iff per-block
// window is L2-resident (R8 k_csr, 40KB window), ~17 G/s wall when spread
// over tens of MB (R11 k_bucket, 40MB window) -> k_bucket now streams
// COALESCED only (block-local counting sort); the only scattered stores left
// are k_csr's 40KB-window csr writes. Fill=44us harness floor.

__device__ __forceinline__ u16 f2bf(float f) {
    unsigned u = __float_as_uint(f);
    unsigned r = (u + 0x7fffu + ((u >> 16) & 1u)) >> 16;   // round-to-nearest-even
    return (u16)r;
}

// ---- K1 (k_bucket): block-local counting sort by dst-range + fused gemm ----
// Edge blocks: count -> LDS prefix scan -> LDS scatter (sorted by range) ->
// fully-coalesced stream-out of records + 501-entry offset table. EXACT
// (no cell caps). Zero global atomics, zero scattered global stores.

__global__ void __launch_bounds__(256) k_bucket(
    const int* __restrict__ src, const int* __restrict__ dst,
    const float* __restrict__ ew, const float* __restrict__ x,
    const float* __restrict__ W, u16* __restrict__ h_bf,
    ull* __restrict__ grecs, u32* __restrict__ offs)
{
    extern __shared__ char smem[];
    const int t = threadIdx.x;

    if (blockIdx.x < CHUNKS) {
        // ---- edge path ----
        u32* rcnt   = (u32*)smem;                     // [512] counts (500 used)
        u32* ping   = (u32*)(smem + 2048);            // [512] scan ping
        u32* pong   = (u32*)(smem + 4096);            // [512] scan pong
        ull* sorted = (ull*)(smem + 6144);            // [1250] records by range

        for (int i = t; i < 512; i += 256) rcnt[i] = 0;
        __syncthreads();

        // phase A: load edges, reserve local slot per range, stash in regs
        const int e0 = blockIdx.x * EPC;
        u32 rs[5]; ull rec[5];
        #pragma unroll
        for (int i = 0; i < 5; ++i) {                 // 5*256 = 1280 >= 1250
            int idx = i * 256 + t;
            rs[i] = 0xffffffffu;
            if (idx < EPC) {
                int e = e0 + idx;
                int d = dst[e];
                int s = src[e];
                float w = ew[e];
                int r = d / RW;                       // magic-mul
                int bin = d - r * RW;                 // 0..19 (5 bits)
                u32 slot = atomicAdd(&rcnt[r], 1u);   // LDS return-atomic (CU-local)
                rs[i] = ((u32)r << 11) | slot;        // slot < 1250 < 2048
                rec[i] = ((ull)__float_as_uint(w) << 32) | ((u32)s << 5) | (u32)bin;
            }
        }
        __syncthreads();

        // phase B: inclusive Hillis-Steele scan of rcnt[512] (9 steps)
        u32* a = ping; u32* bq = pong;
        for (int i = t; i < 512; i += 256) a[i] = rcnt[i];
        __syncthreads();
        for (int dd = 1; dd < 512; dd <<= 1) {
            for (int i = t; i < 512; i += 256)
                bq[i] = a[i] + ((i >= dd) ? a[i - dd] : 0u);
            __syncthreads();
            u32* tmp = a; a = bq; bq = tmp;           // result ends in 'a'
        }

        // phase C: scatter records into LDS at start[r] + slot
        #pragma unroll
        for (int i = 0; i < 5; ++i) {
            if (rs[i] != 0xffffffffu) {
                int r = (int)(rs[i] >> 11);
                int slot = (int)(rs[i] & 2047u);
                sorted[a[r] - rcnt[r] + slot] = rec[i];
            }
        }
        __syncthreads();

        // phase D: coalesced stream-out (625 x 16B) + offset table (501 x 4B)
        {
            const uint4* sp = (const uint4*)sorted;
            uint4* gp = (uint4*)(grecs + (size_t)blockIdx.x * EPC);
            for (int i = t; i < EPC / 2; i += 256) gp[i] = sp[i];
            u32* ob = offs + (size_t)blockIdx.x * 512;
            for (int i = t; i < NR; i += 256) ob[i] = a[i] - rcnt[i];  // exclusive start
            if (t == 0) ob[NR] = EPC;                 // total (all edges kept)
        }
    } else {
        // ---- gemm path (overlaps): h = x @ W^T -> bf16, 32 nodes/block ----
        float* xs = (float*)smem;                     // [32][128] = 16 KB
        const int node0 = (blockIdx.x - CHUNKS) * GEMM_NPB;
        const int col = t & 127;
        const int half = t >> 7;

        #pragma unroll
        for (int r = 0; r < 16; ++r) {
            int row = half * 16 + r;
            int n = node0 + row;
            xs[row * D + col] = (n < N_NODES) ? x[n * D + col] : 0.0f;
        }
        __syncthreads();

        float acc[16];
        #pragma unroll
        for (int r = 0; r < 16; ++r) acc[r] = 0.0f;

        const float4* Wrow = (const float4*)&W[col * D];
        const float* xbase = &xs[half * 16 * D];
        for (int k4 = 0; k4 < D / 4; ++k4) {
            float4 w = Wrow[k4];
            int k = k4 * 4;
            #pragma unroll
            for (int r = 0; r < 16; ++r) {
                acc[r] += xbase[r * D + k + 0] * w.x;
                acc[r] += xbase[r * D + k + 1] * w.y;
                acc[r] += xbase[r * D + k + 2] * w.z;
                acc[r] += xbase[r * D + k + 3] * w.w;
            }
        }
        #pragma unroll
        for (int r = 0; r < 16; ++r) {
            int n = node0 + half * 16 + r;
            if (n < N_NODES) h_bf[n * D + col] = f2bf(acc[r]);
        }
    }
}

// ---- K2 (k_csr): thread t = chunk t; segment gather -> 40KB-window rank ----
// Per block (range r): each thread reads its chunk's [off, off+1) pair and its
// tiny contiguous record segment (scattered READS, L2-friendly: offs 1MB,
// grecs 5MB), ranks via packed LDS return-atomics, stores csr records into
// this range's 40KB window (L2-resident scatter - the proven-cheap kind).

__global__ void __launch_bounds__(512) k_csr(
    const ull* __restrict__ grecs, const u32* __restrict__ offs,
    u32* __restrict__ gpacked, float* __restrict__ dinv, ull* __restrict__ csr)
{
    __shared__ u32 bcnt[RW];                          // packed count<<25 | ewsum_7.18
    const int t = threadIdx.x;                        // chunk id (512 == CHUNKS)
    const int r = blockIdx.x;

    if (t < RW) bcnt[t] = 0;

    const u32* ob = offs + (size_t)t * 512;
    u32 o0 = ob[r], o1 = ob[r + 1];
    if (o0 > EPC) o0 = EPC;                           // hardening
    if (o1 > EPC) o1 = EPC;
    int cnt = (int)o1 - (int)o0;
    if (cnt < 0) cnt = 0;
    if (cnt > 64) cnt = 64;                           // Poisson(2.5) max ~16; hard bound
    __syncthreads();                                  // bcnt init visible

    const ull* seg = grecs + (size_t)t * EPC + o0;
    for (int j = 0; j < cnt; ++j) {
        ull v = seg[j];
        u32 lo = (u32)v;
        int bin = (int)(lo & 31u);                    // 0..19
        u32 srcn = lo >> 5;
        u32 wb = (u32)(v >> 32);
        float w = __uint_as_float(wb);
        u32 add = (1u << 25) | (u32)(w * EWFX);
        u32 old = atomicAdd(&bcnt[bin], add);         // LDS return-atomic
        int pos = (int)(old >> 25);
        if (pos < CAP) {
            int dstg = r * RW + bin;
            csr[(size_t)dstg * CAP + pos] = ((ull)wb << 32) | srcn;
        }
    }
    __syncthreads();

    if (t < RW) {
        int n = r * RW + t;
        u32 v = bcnt[t];
        gpacked[n] = v;
        dinv[n] = rsqrtf(1.0f + (float)(v & EWM) * 0x1p-18f);
    }
}

// ---- K3 (k_agg): one WAVE per node (byte-identical to R8's best) ----

#define AGG_NPB 4                         // nodes (waves) per 256-thread block

__global__ void __launch_bounds__(256) k_agg(
    const u32* __restrict__ gpacked, const float* __restrict__ dinv,
    const ull* __restrict__ csr, const u16* __restrict__ h_bf,
    const float* __restrict__ b, float* __restrict__ out)
{
    const int wid  = threadIdx.x >> 6;
    const int lane = threadIdx.x & 63;
    const int n = blockIdx.x * AGG_NPB + wid;   // 2500*4 = 10000 exact

    __shared__ ull sm[AGG_NPB][CAP];            // packed (norm_f32 << 32) | src

    const int deg = (int)(gpacked[n] >> 25);
    const float dn = dinv[n];
    const ull* bucket = csr + (size_t)n * CAP;

    #pragma unroll
    for (int r = 0; r < 2; ++r) {
        int j = r * 64 + lane;
        if (j < deg) {
            ull v = bucket[j];
            int s = (int)(u32)(v & 0xffffffffu);
            float w = __uint_as_float((u32)(v >> 32));
            float nm = dinv[s] * w * dn;        // table gather, 40KB L2-hot
            sm[wid][j] = ((ull)__float_as_uint(nm) << 32) | (u32)s;
        }
    }
    __syncthreads();                            // setup->mainloop; waves independent after

    float acc0 = 0.0f, acc1 = 0.0f;
    const ull* smw = sm[wid];
    #pragma unroll 4
    for (int j = 0; j < deg; ++j) {
        ull v = smw[j];                         // same addr across wave -> LDS broadcast
        int s = (int)(u32)v;
        float nm = __uint_as_float((u32)(v >> 32));
        u32 hc = *(const u32*)(h_bf + (size_t)s * D + lane * 2);  // 2 bf16 cols
        acc0 += __uint_as_float(hc << 16) * nm;
        acc1 += __uint_as_float(hc & 0xffff0000u) * nm;
    }

    // self loop + bias, write 8B/lane (512B/wave contiguous)
    float s2 = dn * dn;
    u32 hs = *(const u32*)(h_bf + (size_t)n * D + lane * 2);
    acc0 += __uint_as_float(hs << 16) * s2;
    acc1 += __uint_as_float(hs & 0xffff0000u) * s2;
    float2 bb = *(const float2*)(b + lane * 2);
    float2 o;
    o.x = acc0 + bb.x;
    o.y = acc1 + bb.y;
    *(float2*)(out + (size_t)n * D + lane * 2) = o;
}

// ---------------- launch ----------------

extern "C" void kernel_launch(void* const* d_in, const int* in_sizes, int n_in,
                              void* d_out, int out_size, void* d_ws, size_t ws_size,
                              hipStream_t stream) {
    const float* x  = (const float*)d_in[0];
    const float* W  = (const float*)d_in[1];
    const float* b  = (const float*)d_in[2];
    const float* ew = (const float*)d_in[3];
    const int* ei   = (const int*)d_in[4];
    const int* src = ei;
    const int* dst = ei + N_EDGES;
    float* out = (float*)d_out;

    // workspace layout (bytes), ws >= 268 MB per fillBuffer evidence:
    // gpacked u32[10000]            [0,        40000)
    // dinv    f32[10000]            [40000,    80000)
    // h_bf    u16[10000*128]        [80000,    2640000)
    // csr     u64[10000*128]        [2640000,  12880000)
    // grecs   u64[640000]           [12880000, 18000000)
    // offs    u32[512*512]          [18000000, 19048576)
    char* ws = (char*)d_ws;
    u32*   gpacked = (u32*)(ws);
    float* dinv    = (float*)(ws + 40000);
    u16*   h_bf    = (u16*)(ws + 80000);
    ull*   csr     = (ull*)(ws + 2640000);
    ull*   grecs   = (ull*)(ws + 12880000);
    u32*   offs    = (u32*)(ws + 18000000);

    k_bucket<<<CHUNKS + GEMM_BLOCKS, 256, SMEM_K1, stream>>>(
        src, dst, ew, x, W, h_bf, grecs, offs);
    k_csr<<<NR, 512, 0, stream>>>(grecs, offs, gpacked, dinv, csr);
    k_agg<<<N_NODES / AGG_NPB, 256, 0, stream>>>(gpacked, dinv, csr, h_bf, b, out);
}